// Round 4
// baseline (303.985 us; speedup 1.0000x reference)
//
#include <hip/hip_runtime.h>

#define EMB 64
#define RAD 32
#define CUTOFF_F 5.0f

typedef float f32x4 __attribute__((ext_vector_type(4)));

// ---------------------------------------------------------------------------
// Kernel 1: per-species projected embeddings.
// pA[s][k] = sum_j z_embed[s][j] * z_map_w[k][j]
// pB[s][k] = sum_j z_embed[s][j] * z_map_w[k][64+j]
// ---------------------------------------------------------------------------
__global__ void species_proj_kernel(const float* __restrict__ z_embed,
                                    const float* __restrict__ z_map_w,
                                    float* __restrict__ pA,
                                    float* __restrict__ pB) {
    const int s = blockIdx.x;
    const int k = threadIdx.x;  // 0..63
    const float* ze = z_embed + s * EMB;
    const float* wk = z_map_w + k * (2 * EMB);
    float a = 0.f, b = 0.f;
#pragma unroll 8
    for (int j = 0; j < EMB; ++j) {
        const float e = ze[j];
        a = fmaf(e, wk[j], a);
        b = fmaf(e, wk[EMB + j], b);
    }
    pA[s * EMB + k] = a;
    pB[s * EMB + k] = b;
}

// ---------------------------------------------------------------------------
// Kernel 2: fused edge embedding. One wave per edge-chunk, lane = channel.
// Each wave owns a CONTIGUOUS range of edges so its three output streams are
// sequential (L2 write-combining friendly). Plain (cached) stores — L2 smooths
// the write bursts into full HBM rows; nt stores measured slower.
// ---------------------------------------------------------------------------
__global__ __launch_bounds__(256) void edge_embed_kernel(
    const int* __restrict__ Z,
    const int* __restrict__ nbr,    // [E][2]
    const float* __restrict__ nv,   // [E][3]
    const float* __restrict__ rmw,  // [192][32]
    const float* __restrict__ rmb,  // [192]
    const float* __restrict__ rbfc, // [32]
    const float* __restrict__ rbfb, // [32]
    const float* __restrict__ pA,   // [S][64]
    const float* __restrict__ pB,   // [S][64]
    float* __restrict__ out,
    int E) {
    __shared__ __align__(16) float buf[4][3 * EMB * 9];  // per-wave staging

    const int tid  = threadIdx.x;
    const int w    = tid >> 6;
    const int lane = tid & 63;

    // Radial weights for this lane's 3 output channels -> registers (96 VGPRs).
    float W0[RAD], W1[RAD], W2[RAD];
#pragma unroll
    for (int j = 0; j < RAD; ++j) {
        W0[j] = rmw[lane * RAD + j];
        W1[j] = rmw[(lane + EMB) * RAD + j];
        W2[j] = rmw[(lane + 2 * EMB) * RAD + j];
    }
    const float b0 = rmb[lane], b1 = rmb[lane + EMB], b2 = rmb[lane + 2 * EMB];
    const float cj = rbfc[lane & (RAD - 1)];
    const float bj = rbfb[lane & (RAD - 1)];

    float* bw = buf[w];
    // Static zero slots written once (I off-diagonals, A diagonal).
    {
        const int o = lane * 9;
        bw[o + 1] = 0.f; bw[o + 2] = 0.f; bw[o + 3] = 0.f;
        bw[o + 5] = 0.f; bw[o + 6] = 0.f; bw[o + 7] = 0.f;
        bw[576 + o + 0] = 0.f; bw[576 + o + 4] = 0.f; bw[576 + o + 8] = 0.f;
    }

    const size_t strideT = (size_t)E * (EMB * 9);
    const int nw    = gridDim.x * 4;
    const int chunk = (E + nw - 1) / nw;
    const int gw    = blockIdx.x * 4 + w;

    int       e    = __builtin_amdgcn_readfirstlane(gw * chunk);
    const int eEnd = __builtin_amdgcn_readfirstlane(min(e + chunk, E));
    if (e >= eEnd) return;

    // ---- pipeline prologue: fully load edge e ----
    int   i0 = nbr[2 * e], i1 = nbr[2 * e + 1];
    float vx = nv[3 * e], vy = nv[3 * e + 1], vz = nv[3 * e + 2];
    int   s0 = Z[i0], s1 = Z[i1];
    float hA = pA[s0 * EMB + lane], hB = pB[s1 * EMB + lane];

    while (true) {
        const int  en   = e + 1;
        const bool more = en < eEnd;

        // next edge: stage A (independent loads) — issue ASAP (L1-adjacent)
        int ni0 = 0, ni1 = 0;
        float nvx = 0.f, nvy = 0.f, nvz = 0.f;
        if (more) {
            ni0 = nbr[2 * en]; ni1 = nbr[2 * en + 1];
            nvx = nv[3 * en]; nvy = nv[3 * en + 1]; nvz = nv[3 * en + 2];
        }

        // current edge: geometry + radial basis
        const float r2   = vx * vx + vy * vy + vz * vz;
        const float rinv = rsqrtf(r2);
        const float r    = r2 * rinv;
        const float x = vx * rinv, y = vy * rinv, z = vz * rinv;

        float env = 0.f;
        if (r < CUTOFF_F)
            env = 0.5f * (__cosf(0.6283185307f * r) + 1.0f);

        const float t = __expf(-r);
        const float d = t - cj;
        const float g = __expf(-bj * d * d);  // lane holds expansion[lane&31]

        // next edge: stage B (species lookup, depends on stage A)
        int ns0 = 0, ns1 = 0;
        if (more) { ns0 = Z[ni0]; ns1 = Z[ni1]; }

        // radial matvec: c_pre[m] = sum_j g[j]*Wr[m][j] + b[m]
        float aI = b0, aA = b1, aS = b2;
#pragma unroll
        for (int j = 0; j < RAD; ++j) {
            const float gj =
                __int_as_float(__builtin_amdgcn_readlane(__float_as_int(g), j));
            aI = fmaf(gj, W0[j], aI);
            aA = fmaf(gj, W1[j], aA);
            aS = fmaf(gj, W2[j], aS);
        }

        // next edge: stage C (embedding gather, depends on stage B)
        float nhA = 0.f, nhB = 0.f;
        if (more) { nhA = pA[ns0 * EMB + lane]; nhB = pB[ns1 * EMB + lane]; }

        const float eh = env * (hA + hB);
        const float cI = aI * eh, cA = aA * eh, cS = aS * eh;

        // Stage this edge's 3x(64x9) block into LDS (only non-static slots).
        const int o = lane * 9;
        bw[o + 0] = cI; bw[o + 4] = cI; bw[o + 8] = cI;

        bw[576 + o + 1] = -z * cA; bw[576 + o + 2] =  y * cA;
        bw[576 + o + 3] =  z * cA; bw[576 + o + 5] = -x * cA;
        bw[576 + o + 6] = -y * cA; bw[576 + o + 7] =  x * cA;

        const float m = (x * x + y * y + z * z) * (1.f / 3.f);
        bw[1152 + o + 0] = (x * x - m) * cS;
        bw[1152 + o + 1] = x * y * cS;
        bw[1152 + o + 2] = x * z * cS;
        bw[1152 + o + 3] = x * y * cS;
        bw[1152 + o + 4] = (y * y - m) * cS;
        bw[1152 + o + 5] = y * z * cS;
        bw[1152 + o + 6] = x * z * cS;
        bw[1152 + o + 7] = y * z * cS;
        bw[1152 + o + 8] = (z * z - m) * cS;

        // Coalesced store: 3 tensors x 144 float4 each (plain, through L2).
        const size_t ebase = (size_t)e * (EMB * 9);
#pragma unroll
        for (int ts = 0; ts < 3; ++ts) {
#pragma unroll
            for (int i = 0; i < 3; ++i) {
                const int q = lane + (i << 6);
                if (q < 144) {
                    const f32x4 v =
                        *reinterpret_cast<const f32x4*>(bw + ts * 576 + 4 * q);
                    *reinterpret_cast<f32x4*>(out + strideT * ts + ebase + 4 * q) = v;
                }
            }
        }

        if (!more) break;
        e = en;
        vx = nvx; vy = nvy; vz = nvz;
        hA = nhA; hB = nhB;
    }
}

extern "C" void kernel_launch(void* const* d_in, const int* in_sizes, int n_in,
                              void* d_out, int out_size, void* d_ws, size_t ws_size,
                              hipStream_t stream) {
    const int*   Z       = (const int*)d_in[0];
    const int*   nbr     = (const int*)d_in[1];
    const float* nv      = (const float*)d_in[2];
    const float* z_embed = (const float*)d_in[3];
    const float* z_map_w = (const float*)d_in[4];
    const float* rmw     = (const float*)d_in[5];
    const float* rmb     = (const float*)d_in[6];
    const float* rbfc    = (const float*)d_in[7];
    const float* rbfb    = (const float*)d_in[8];
    float*       out     = (float*)d_out;

    const int E         = in_sizes[2] / 3;
    const int n_species = in_sizes[3] / EMB;

    float* pA = (float*)d_ws;
    float* pB = pA + (size_t)n_species * EMB;

    species_proj_kernel<<<n_species, EMB, 0, stream>>>(z_embed, z_map_w, pA, pB);
    edge_embed_kernel<<<2000, 256, 0, stream>>>(Z, nbr, nv, rmw, rmb, rbfc, rbfb,
                                                pA, pB, out, E);
}

// Round 5
// 279.450 us; speedup vs baseline: 1.0878x; 1.0878x over previous
//
#include <hip/hip_runtime.h>

#define EMB 64
#define RAD 32
#define CUTOFF_F 5.0f

typedef float f32x4 __attribute__((ext_vector_type(4)));

// ---------------------------------------------------------------------------
// Kernel 1: per-species projected embeddings.
// pA[s][k] = sum_j z_embed[s][j] * z_map_w[k][j]
// pB[s][k] = sum_j z_embed[s][j] * z_map_w[k][64+j]
// ---------------------------------------------------------------------------
__global__ void species_proj_kernel(const float* __restrict__ z_embed,
                                    const float* __restrict__ z_map_w,
                                    float* __restrict__ pA,
                                    float* __restrict__ pB) {
    const int s = blockIdx.x;
    const int k = threadIdx.x;  // 0..63
    const float* ze = z_embed + s * EMB;
    const float* wk = z_map_w + k * (2 * EMB);
    float a = 0.f, b = 0.f;
#pragma unroll 8
    for (int j = 0; j < EMB; ++j) {
        const float e = ze[j];
        a = fmaf(e, wk[j], a);
        b = fmaf(e, wk[EMB + j], b);
    }
    pA[s * EMB + k] = a;
    pB[s * EMB + k] = b;
}

// ---------------------------------------------------------------------------
// Kernel 2: fused edge embedding. One wave (64 lanes) per edge, lane = channel.
// ROUND-ROBIN edge assignment (e += nw): concurrent waves write adjacent
// output blocks -> dense global write front -> L2/MC merges into full HBM
// rows (matches the 6.5 TB/s fill-kernel pattern). A/B vs round 3: stores are
// PLAIN (cached) instead of nontemporal — the only change.
// ---------------------------------------------------------------------------
__global__ __launch_bounds__(256) void edge_embed_kernel(
    const int* __restrict__ Z,
    const int* __restrict__ nbr,    // [E][2]
    const float* __restrict__ nv,   // [E][3]
    const float* __restrict__ rmw,  // [192][32]
    const float* __restrict__ rmb,  // [192]
    const float* __restrict__ rbfc, // [32]
    const float* __restrict__ rbfb, // [32]
    const float* __restrict__ pA,   // [S][64]
    const float* __restrict__ pB,   // [S][64]
    float* __restrict__ out,
    int E) {
    __shared__ __align__(16) float buf[4][3 * EMB * 9];  // per-wave staging

    const int tid  = threadIdx.x;
    const int w    = tid >> 6;
    const int lane = tid & 63;

    // Radial weights for this lane's 3 output channels -> registers (96 VGPRs).
    float W0[RAD], W1[RAD], W2[RAD];
#pragma unroll
    for (int j = 0; j < RAD; ++j) {
        W0[j] = rmw[lane * RAD + j];
        W1[j] = rmw[(lane + EMB) * RAD + j];
        W2[j] = rmw[(lane + 2 * EMB) * RAD + j];
    }
    const float b0 = rmb[lane], b1 = rmb[lane + EMB], b2 = rmb[lane + 2 * EMB];
    const float cj = rbfc[lane & (RAD - 1)];
    const float bj = rbfb[lane & (RAD - 1)];

    float* bw = buf[w];
    // Static zero slots written once (I off-diagonals, A diagonal).
    {
        const int o = lane * 9;
        bw[o + 1] = 0.f; bw[o + 2] = 0.f; bw[o + 3] = 0.f;
        bw[o + 5] = 0.f; bw[o + 6] = 0.f; bw[o + 7] = 0.f;
        bw[576 + o + 0] = 0.f; bw[576 + o + 4] = 0.f; bw[576 + o + 8] = 0.f;
    }

    const size_t strideT = (size_t)E * (EMB * 9);
    const int nw = gridDim.x * 4;
    int e = __builtin_amdgcn_readfirstlane(blockIdx.x * 4 + w);
    if (e >= E) return;

    // ---- pipeline prologue: fully load edge e ----
    int   i0 = nbr[2 * e], i1 = nbr[2 * e + 1];
    float vx = nv[3 * e], vy = nv[3 * e + 1], vz = nv[3 * e + 2];
    int   s0 = Z[i0], s1 = Z[i1];
    float hA = pA[s0 * EMB + lane], hB = pB[s1 * EMB + lane];

    while (true) {
        const int  en   = __builtin_amdgcn_readfirstlane(e + nw);
        const bool more = en < E;

        // next edge: stage A (independent loads) — issue ASAP
        int ni0 = 0, ni1 = 0;
        float nvx = 0.f, nvy = 0.f, nvz = 0.f;
        if (more) {
            ni0 = nbr[2 * en]; ni1 = nbr[2 * en + 1];
            nvx = nv[3 * en]; nvy = nv[3 * en + 1]; nvz = nv[3 * en + 2];
        }

        // current edge: geometry + radial basis
        const float r2   = vx * vx + vy * vy + vz * vz;
        const float rinv = rsqrtf(r2);
        const float r    = r2 * rinv;
        const float x = vx * rinv, y = vy * rinv, z = vz * rinv;

        float env = 0.f;
        if (r < CUTOFF_F)
            env = 0.5f * (__cosf(0.6283185307f * r) + 1.0f);

        const float t = __expf(-r);
        const float d = t - cj;
        const float g = __expf(-bj * d * d);  // lane holds expansion[lane&31]

        // next edge: stage B (species lookup, depends on stage A)
        int ns0 = 0, ns1 = 0;
        if (more) { ns0 = Z[ni0]; ns1 = Z[ni1]; }

        // radial matvec: c_pre[m] = sum_j g[j]*Wr[m][j] + b[m]
        float aI = b0, aA = b1, aS = b2;
#pragma unroll
        for (int j = 0; j < RAD; ++j) {
            const float gj =
                __int_as_float(__builtin_amdgcn_readlane(__float_as_int(g), j));
            aI = fmaf(gj, W0[j], aI);
            aA = fmaf(gj, W1[j], aA);
            aS = fmaf(gj, W2[j], aS);
        }

        // next edge: stage C (embedding gather, depends on stage B)
        float nhA = 0.f, nhB = 0.f;
        if (more) { nhA = pA[ns0 * EMB + lane]; nhB = pB[ns1 * EMB + lane]; }

        const float eh = env * (hA + hB);
        const float cI = aI * eh, cA = aA * eh, cS = aS * eh;

        // Stage this edge's 3x(64x9) block into LDS (only non-static slots).
        const int o = lane * 9;
        bw[o + 0] = cI; bw[o + 4] = cI; bw[o + 8] = cI;

        bw[576 + o + 1] = -z * cA; bw[576 + o + 2] =  y * cA;
        bw[576 + o + 3] =  z * cA; bw[576 + o + 5] = -x * cA;
        bw[576 + o + 6] = -y * cA; bw[576 + o + 7] =  x * cA;

        const float m = (x * x + y * y + z * z) * (1.f / 3.f);
        bw[1152 + o + 0] = (x * x - m) * cS;
        bw[1152 + o + 1] = x * y * cS;
        bw[1152 + o + 2] = x * z * cS;
        bw[1152 + o + 3] = x * y * cS;
        bw[1152 + o + 4] = (y * y - m) * cS;
        bw[1152 + o + 5] = y * z * cS;
        bw[1152 + o + 6] = x * z * cS;
        bw[1152 + o + 7] = y * z * cS;
        bw[1152 + o + 8] = (z * z - m) * cS;

        // Coalesced store: 3 tensors x 144 float4 each (plain, through L2).
        const size_t ebase = (size_t)e * (EMB * 9);
#pragma unroll
        for (int ts = 0; ts < 3; ++ts) {
#pragma unroll
            for (int i = 0; i < 3; ++i) {
                const int q = lane + (i << 6);
                if (q < 144) {
                    const f32x4 v =
                        *reinterpret_cast<const f32x4*>(bw + ts * 576 + 4 * q);
                    *reinterpret_cast<f32x4*>(out + strideT * ts + ebase + 4 * q) = v;
                }
            }
        }

        if (!more) break;
        e = en;
        vx = nvx; vy = nvy; vz = nvz;
        hA = nhA; hB = nhB;
    }
}

extern "C" void kernel_launch(void* const* d_in, const int* in_sizes, int n_in,
                              void* d_out, int out_size, void* d_ws, size_t ws_size,
                              hipStream_t stream) {
    const int*   Z       = (const int*)d_in[0];
    const int*   nbr     = (const int*)d_in[1];
    const float* nv      = (const float*)d_in[2];
    const float* z_embed = (const float*)d_in[3];
    const float* z_map_w = (const float*)d_in[4];
    const float* rmw     = (const float*)d_in[5];
    const float* rmb     = (const float*)d_in[6];
    const float* rbfc    = (const float*)d_in[7];
    const float* rbfb    = (const float*)d_in[8];
    float*       out     = (float*)d_out;

    const int E         = in_sizes[2] / 3;
    const int n_species = in_sizes[3] / EMB;

    float* pA = (float*)d_ws;
    float* pB = pA + (size_t)n_species * EMB;

    species_proj_kernel<<<n_species, EMB, 0, stream>>>(z_embed, z_map_w, pA, pB);
    edge_embed_kernel<<<2000, 256, 0, stream>>>(Z, nbr, nv, rmw, rmb, rbfc, rbfb,
                                                pA, pB, out, E);
}